// Round 7
// baseline (495.781 us; speedup 1.0000x reference)
//
#include <hip/hip_runtime.h>
#include <hip/hip_bf16.h>

// ---------------------------------------------------------------------------
// GCN forward: 2x GCNConv (MFMA bf16x3 GEMM + CSR gather aggregation)
//              + segment_max + log_softmax
// ---------------------------------------------------------------------------

typedef __attribute__((ext_vector_type(4))) float f32x4;
typedef __attribute__((ext_vector_type(8))) short s16x8;

__device__ inline unsigned short f32_to_bf16_rn(float x) {
    unsigned u = __builtin_bit_cast(unsigned, x);
    unsigned r = u + 0x7FFFu + ((u >> 16) & 1u);
    return (unsigned short)(r >> 16);
}
__device__ inline float bf16_to_f32(unsigned short h) {
    unsigned u = ((unsigned)h) << 16;
    return __builtin_bit_cast(float, u);
}
__device__ inline f32x4 max4(f32x4 a, f32x4 b) {
    f32x4 r;
#pragma unroll
    for (int j = 0; j < 4; ++j) r[j] = fmaxf(a[j], b[j]);
    return r;
}

// ---------------- CSR build ----------------

__global__ __launch_bounds__(256) void count_kernel(const int* __restrict__ dst,
                                                    int* __restrict__ indeg, int E) {
    int e = blockIdx.x * 256 + threadIdx.x;
    if (e < E) atomicAdd(&indeg[dst[e]], 1);
}

__global__ __launch_bounds__(256) void scanA(const int* __restrict__ in,
                                             int* __restrict__ out,
                                             int* __restrict__ bsum, int N) {
    __shared__ int tmp[256];
    int t = threadIdx.x;
    int g = blockIdx.x * 256 + t;
    int v = (g < N) ? in[g] : 0;
    tmp[t] = v;
    __syncthreads();
#pragma unroll
    for (int off = 1; off < 256; off <<= 1) {
        int add = (t >= off) ? tmp[t - off] : 0;
        __syncthreads();
        if (t >= off) tmp[t] += add;
        __syncthreads();
    }
    if (g < N) out[g] = tmp[t] - v;   // exclusive within block
    if (t == 255) bsum[blockIdx.x] = tmp[255];
}

__global__ __launch_bounds__(256) void scanB(int* __restrict__ bsum, int nb) {
    __shared__ int tmp[256];
    int t = threadIdx.x;
    int v = (t < nb) ? bsum[t] : 0;
    tmp[t] = v;
    __syncthreads();
#pragma unroll
    for (int off = 1; off < 256; off <<= 1) {
        int add = (t >= off) ? tmp[t - off] : 0;
        __syncthreads();
        if (t >= off) tmp[t] += add;
        __syncthreads();
    }
    if (t < nb) bsum[t] = tmp[t] - v;  // exclusive
}

__global__ __launch_bounds__(256) void scanC(int* __restrict__ rowstart,
                                             const int* __restrict__ bsum,
                                             int N, int E) {
    int g = blockIdx.x * 256 + threadIdx.x;
    if (g < N) rowstart[g] += bsum[blockIdx.x];
    if (g == 0) rowstart[N] = E;
}

__global__ __launch_bounds__(256) void dinv_kernel(const int* __restrict__ indeg,
                                                   float* __restrict__ dinv, int N) {
    int i = blockIdx.x * 256 + threadIdx.x;
    if (i < N) dinv[i] = rsqrtf((float)(indeg[i] + 1));  // +1 self loop
}

__global__ __launch_bounds__(256) void fill_csr(const int* __restrict__ src,
                                                const int* __restrict__ dst,
                                                const int* __restrict__ rowstart,
                                                int* __restrict__ fill,
                                                int* __restrict__ csr_src, int E) {
    int e = blockIdx.x * 256 + threadIdx.x;
    if (e < E) {
        int d = dst[e];
        int p = rowstart[d] + atomicAdd(&fill[d], 1);
        csr_src[p] = src[e];
    }
}

__global__ __launch_bounds__(256) void gstart_kernel(const int* __restrict__ batch,
                                                     int* __restrict__ gstart,
                                                     int N, int G) {
    int g = blockIdx.x * 256 + threadIdx.x;
    if (g > G) return;
    if (g == G) { gstart[G] = N; return; }
    int lo = 0, hi = N;
    while (lo < hi) {
        int mid = (lo + hi) >> 1;
        if (batch[mid] < g) lo = mid + 1; else hi = mid;
    }
    gstart[g] = lo;
}

// ---------------- weight pre-split: W[K][256] f32 -> packed bf16 hi/lo ------
// Wh/Wl layout: [K/32][256][32]  (k-tile, col, k-within) so GEMM B-staging is
// a coalesced linear copy per k-tile.
__global__ __launch_bounds__(256) void conv_w(const float* __restrict__ W,
                                              unsigned short* __restrict__ Wh,
                                              unsigned short* __restrict__ Wl,
                                              int K) {
    int idx = blockIdx.x * 256 + threadIdx.x;  // over K*256
    if (idx >= K * 256) return;
    int k = idx >> 8, c = idx & 255;
    float w = W[idx];
    unsigned short h = f32_to_bf16_rn(w);
    float lo = w - bf16_to_f32(h);
    unsigned short l = f32_to_bf16_rn(lo);
    size_t o = ((size_t)(k >> 5) * 256 + c) * 32 + (k & 31);
    Wh[o] = h;
    Wl[o] = l;
}

// ---------------- MFMA GEMM: out[row] = (A[row] @ W) * scale[row] -----------
// A:[M,K] f32, W pre-split bf16 hi/lo packed [K/32][256][32], out:[M,256] f32.
// bf16x3: (ah+al)(bh+bl) ~= ah*bh + al*bh + ah*bl  (residual ~2^-16 rel).
// Block: 64 rows x 256 cols, 4 waves; wave w owns cols [w*64, w*64+64).
// C/D map (verified m89/m91): col=lane&15, row=(lane>>4)*4+reg.
// A/B k-chunk permutation is self-cancelling (same bijection on both sides).
template <int K>
__global__ __launch_bounds__(256, 3) void gemm_mfma(const float* __restrict__ A,
                                                    const unsigned short* __restrict__ Bh,
                                                    const unsigned short* __restrict__ Bl,
                                                    const float* __restrict__ scale,
                                                    float* __restrict__ out, int M) {
    constexpr int LDT = 40;  // padded row (bf16 elems): 80 B -> ~2-way banks
    __shared__ __align__(16) unsigned short Ah[64 * LDT];
    __shared__ __align__(16) unsigned short Al[64 * LDT];
    __shared__ __align__(16) unsigned short BhT[256 * LDT];
    __shared__ __align__(16) unsigned short BlT[256 * LDT];

    const int tid  = threadIdx.x;
    const int lane = tid & 63;
    const int w    = tid >> 6;
    const int row0 = blockIdx.x * 64;
    const int q    = lane >> 4;
    const int r16  = lane & 15;

    f32x4 acc[4][4] = {};

    for (int k0 = 0; k0 < K; k0 += 32) {
        // ---- stage A tile (64 x 32 f32 -> hi/lo bf16) ----
        {
            int r = tid >> 2;
            int kq = (tid & 3) * 8;
            int grow = row0 + r;
            float4 v0 = make_float4(0.f, 0.f, 0.f, 0.f);
            float4 v1 = make_float4(0.f, 0.f, 0.f, 0.f);
            if (grow < M) {
                const float* ap = &A[(size_t)grow * K + k0 + kq];
                v0 = *reinterpret_cast<const float4*>(ap);
                v1 = *reinterpret_cast<const float4*>(ap + 4);
            }
            float xs[8] = {v0.x, v0.y, v0.z, v0.w, v1.x, v1.y, v1.z, v1.w};
            s16x8 hv, lv;
#pragma unroll
            for (int j = 0; j < 8; ++j) {
                unsigned short h = f32_to_bf16_rn(xs[j]);
                hv[j] = (short)h;
                lv[j] = (short)f32_to_bf16_rn(xs[j] - bf16_to_f32(h));
            }
            *reinterpret_cast<s16x8*>(&Ah[r * LDT + kq]) = hv;
            *reinterpret_cast<s16x8*>(&Al[r * LDT + kq]) = lv;
        }
        // ---- stage B tile (copy packed 256 x 32 bf16 hi/lo, coalesced) ----
        {
            size_t o = ((size_t)(k0 >> 5) * 256 + tid) * 32;
            const s16x8* bsh = reinterpret_cast<const s16x8*>(Bh + o);
            const s16x8* bsl = reinterpret_cast<const s16x8*>(Bl + o);
#pragma unroll
            for (int j = 0; j < 4; ++j) {
                *reinterpret_cast<s16x8*>(&BhT[tid * LDT + j * 8]) = bsh[j];
                *reinterpret_cast<s16x8*>(&BlT[tid * LDT + j * 8]) = bsl[j];
            }
        }
        __syncthreads();

        // ---- compute ----
        s16x8 bh[4], bl[4];
#pragma unroll
        for (int ct = 0; ct < 4; ++ct) {
            int col = w * 64 + ct * 16 + r16;
            bh[ct] = *reinterpret_cast<const s16x8*>(&BhT[col * LDT + q * 8]);
            bl[ct] = *reinterpret_cast<const s16x8*>(&BlT[col * LDT + q * 8]);
        }
#pragma unroll
        for (int rt = 0; rt < 4; ++rt) {
            int rr = rt * 16 + r16;
            s16x8 ah = *reinterpret_cast<const s16x8*>(&Ah[rr * LDT + q * 8]);
            s16x8 al = *reinterpret_cast<const s16x8*>(&Al[rr * LDT + q * 8]);
#pragma unroll
            for (int ct = 0; ct < 4; ++ct) {
                acc[rt][ct] = __builtin_amdgcn_mfma_f32_16x16x32_bf16(ah, bh[ct], acc[rt][ct], 0, 0, 0);
                acc[rt][ct] = __builtin_amdgcn_mfma_f32_16x16x32_bf16(al, bh[ct], acc[rt][ct], 0, 0, 0);
                acc[rt][ct] = __builtin_amdgcn_mfma_f32_16x16x32_bf16(ah, bl[ct], acc[rt][ct], 0, 0, 0);
            }
        }
        __syncthreads();
    }

    // ---- epilogue: scale by dinv[row], store f32 ----
#pragma unroll
    for (int rt = 0; rt < 4; ++rt) {
#pragma unroll
        for (int i = 0; i < 4; ++i) {
            int grow = row0 + rt * 16 + q * 4 + i;
            if (grow < M) {
                float s = scale[grow];
#pragma unroll
                for (int ct = 0; ct < 4; ++ct) {
                    out[(size_t)grow * 256 + w * 64 + ct * 16 + r16] = acc[rt][ct][i] * s;
                }
            }
        }
    }
}

// out[i] = maybe_relu(dinv[i] * (hs[i] + sum_{e: s->i} hs[s]) + bias)
// One WAVE per node: lane loads float4 (16B) -> a full 1KB row per wave-load.
// 4-way edge unroll keeps 4 KB in flight per wave (latency-bound gather fix).
__global__ __launch_bounds__(256) void agg_kernel(const float* __restrict__ hs,
                                                  const int* __restrict__ rowstart,
                                                  const int* __restrict__ csr_src,
                                                  const float* __restrict__ dinv,
                                                  const float* __restrict__ bias,
                                                  float* __restrict__ out,
                                                  int do_relu, int N) {
    int node = blockIdx.x * 4 + (threadIdx.x >> 6);
    if (node >= N) return;
    int lane = threadIdx.x & 63;

    f32x4 a0 = *reinterpret_cast<const f32x4*>(hs + (size_t)node * 256 + lane * 4);
    f32x4 a1 = {}, a2 = {}, a3 = {};
    int e0 = rowstart[node], e1 = rowstart[node + 1];
    int e = e0;
    for (; e + 4 <= e1; e += 4) {
        int s0 = csr_src[e + 0];
        int s1 = csr_src[e + 1];
        int s2 = csr_src[e + 2];
        int s3 = csr_src[e + 3];
        f32x4 v0 = *reinterpret_cast<const f32x4*>(hs + (size_t)s0 * 256 + lane * 4);
        f32x4 v1 = *reinterpret_cast<const f32x4*>(hs + (size_t)s1 * 256 + lane * 4);
        f32x4 v2 = *reinterpret_cast<const f32x4*>(hs + (size_t)s2 * 256 + lane * 4);
        f32x4 v3 = *reinterpret_cast<const f32x4*>(hs + (size_t)s3 * 256 + lane * 4);
        a0 += v0; a1 += v1; a2 += v2; a3 += v3;
    }
    for (; e < e1; ++e) {
        int s = csr_src[e];
        a0 += *reinterpret_cast<const f32x4*>(hs + (size_t)s * 256 + lane * 4);
    }
    f32x4 acc = (a0 + a1) + (a2 + a3);
    float dv = dinv[node];
    f32x4 b = *reinterpret_cast<const f32x4*>(bias + lane * 4);
    f32x4 v;
#pragma unroll
    for (int j = 0; j < 4; ++j) {
        float t = dv * acc[j] + b[j];
        v[j] = do_relu ? fmaxf(t, 0.f) : t;
    }
    *reinterpret_cast<f32x4*>(out + (size_t)node * 256 + lane * 4) = v;
}

// segment max: block per group; 4 waves split the rows; float4 lanes;
// 2 accumulators/wave for load pipelining; LDS reduce across waves.
__global__ __launch_bounds__(256) void pool_kernel(const float* __restrict__ h,
                                                   const int* __restrict__ gstart,
                                                   float* __restrict__ pooled) {
    __shared__ float red[4][256];
    int g = blockIdx.x;
    int w = threadIdx.x >> 6;
    int lane = threadIdx.x & 63;
    int i0 = gstart[g], i1 = gstart[g + 1];
    f32x4 m0 = {-INFINITY, -INFINITY, -INFINITY, -INFINITY};
    f32x4 m1 = m0;
    int i = i0 + w;
    for (; i + 4 < i1; i += 8) {
        f32x4 v0 = *reinterpret_cast<const f32x4*>(h + (size_t)i * 256 + lane * 4);
        f32x4 v1 = *reinterpret_cast<const f32x4*>(h + (size_t)(i + 4) * 256 + lane * 4);
        m0 = max4(m0, v0);
        m1 = max4(m1, v1);
    }
    if (i < i1) {
        f32x4 v0 = *reinterpret_cast<const f32x4*>(h + (size_t)i * 256 + lane * 4);
        m0 = max4(m0, v0);
    }
    m0 = max4(m0, m1);
    *reinterpret_cast<f32x4*>(&red[w][lane * 4]) = m0;
    __syncthreads();
    int t = threadIdx.x;
    float mm = fmaxf(fmaxf(red[0][t], red[1][t]), fmaxf(red[2][t], red[3][t]));
    pooled[(size_t)g * 256 + t] = mm;
}

__global__ __launch_bounds__(256) void lsm_kernel(const float* __restrict__ pooled,
                                                  float* __restrict__ out) {
    __shared__ float red[256];
    int g = blockIdx.x, t = threadIdx.x;
    float v = pooled[(size_t)g * 256 + t];
    red[t] = v;
    __syncthreads();
#pragma unroll
    for (int off = 128; off > 0; off >>= 1) {
        if (t < off) red[t] = fmaxf(red[t], red[t + off]);
        __syncthreads();
    }
    float m = red[0];
    __syncthreads();
    red[t] = expf(v - m);
    __syncthreads();
#pragma unroll
    for (int off = 128; off > 0; off >>= 1) {
        if (t < off) red[t] += red[t + off];
        __syncthreads();
    }
    float s = red[0];
    out[(size_t)g * 256 + t] = v - m - logf(s);
}

extern "C" void kernel_launch(void* const* d_in, const int* in_sizes, int n_in,
                              void* d_out, int out_size, void* d_ws, size_t ws_size,
                              hipStream_t stream) {
    const float* x  = (const float*)d_in[0];
    const float* W1 = (const float*)d_in[1];
    const float* b1 = (const float*)d_in[2];
    const float* W2 = (const float*)d_in[3];
    const float* b2 = (const float*)d_in[4];
    const int* edge_index = (const int*)d_in[5];
    const int* batch = (const int*)d_in[6];
    float* out = (float*)d_out;

    const int N = in_sizes[6];
    const int E = in_sizes[5] / 2;
    const int H = in_sizes[2];        // 256
    const int G = out_size / H;       // 512
    const int K1 = in_sizes[1] / H;   // 128
    const int* src = edge_index;
    const int* dst = edge_index + E;

    // workspace layout
    char* p = (char*)d_ws;
    auto alloc = [&](size_t bytes) {
        char* r = p;
        p += (bytes + 255) & ~(size_t)255;
        return r;
    };
    int*   indeg    = (int*)alloc((size_t)N * 4);
    int*   rowstart = (int*)alloc((size_t)(N + 1) * 4);
    int*   fill     = (int*)alloc((size_t)N * 4);
    int*   bsum     = (int*)alloc(256 * 4);
    float* dinv     = (float*)alloc((size_t)N * 4);
    int*   gstart   = (int*)alloc((size_t)(G + 1) * 4);
    int*   csr_src  = (int*)alloc((size_t)E * 4);
    float* bufA     = (float*)alloc((size_t)N * H * 4);
    float* bufB     = (float*)alloc((size_t)N * H * 4);
    float* pooled   = (float*)alloc((size_t)G * H * 4);
    unsigned short* w1h = (unsigned short*)alloc((size_t)K1 * H * 2);
    unsigned short* w1l = (unsigned short*)alloc((size_t)K1 * H * 2);
    unsigned short* w2h = (unsigned short*)alloc((size_t)H * H * 2);
    unsigned short* w2l = (unsigned short*)alloc((size_t)H * H * 2);

    hipMemsetAsync(indeg, 0, (size_t)N * 4, stream);
    hipMemsetAsync(fill, 0, (size_t)N * 4, stream);

    const int eb = (E + 255) / 256;
    const int nb = (N + 255) / 256;

    count_kernel<<<eb, 256, 0, stream>>>(dst, indeg, E);
    scanA<<<nb, 256, 0, stream>>>(indeg, rowstart, bsum, N);
    scanB<<<1, 256, 0, stream>>>(bsum, nb);
    scanC<<<nb, 256, 0, stream>>>(rowstart, bsum, N, E);
    dinv_kernel<<<nb, 256, 0, stream>>>(indeg, dinv, N);
    fill_csr<<<eb, 256, 0, stream>>>(src, dst, rowstart, fill, csr_src, E);
    gstart_kernel<<<(G + 1 + 255) / 256, 256, 0, stream>>>(batch, gstart, N, G);
    conv_w<<<(K1 * H + 255) / 256, 256, 0, stream>>>(W1, w1h, w1l, K1);
    conv_w<<<(H * H + 255) / 256, 256, 0, stream>>>(W2, w2h, w2l, H);

    const int gb = (N + 63) / 64;
    const int ab = (N + 3) / 4;
    // layer 1: hs = (x @ W1) * dinv[row]; out1 = relu(dinv*(gather+self)+b1)
    gemm_mfma<128><<<gb, 256, 0, stream>>>(x, w1h, w1l, dinv, bufA, N);
    agg_kernel<<<ab, 256, 0, stream>>>(bufA, rowstart, csr_src, dinv, b1, bufB, 1, N);
    // layer 2
    gemm_mfma<256><<<gb, 256, 0, stream>>>(bufB, w2h, w2l, dinv, bufA, N);
    agg_kernel<<<ab, 256, 0, stream>>>(bufA, rowstart, csr_src, dinv, b2, bufB, 0, N);
    // pooling + log_softmax
    pool_kernel<<<G, 256, 0, stream>>>(bufB, gstart, pooled);
    lsm_kernel<<<G, 256, 0, stream>>>(pooled, out);
}

// Round 12
// 374.970 us; speedup vs baseline: 1.3222x; 1.3222x over previous
//
#include <hip/hip_runtime.h>
#include <hip/hip_bf16.h>

// ---------------------------------------------------------------------------
// GCN forward: 2x GCNConv (MFMA bf16x3 GEMM + bf16 CSR gather aggregation)
//              + segment_max + log_softmax
// hs buffers (gathered) are bf16: the random gather is traffic-bound at
// ~4 TB/s (r7 profile), so halving bytes is the only lever.
// ---------------------------------------------------------------------------

typedef __attribute__((ext_vector_type(4))) float f32x4;
typedef __attribute__((ext_vector_type(8))) short s16x8;

__device__ inline unsigned short f32_to_bf16_rn(float x) {
    unsigned u = __builtin_bit_cast(unsigned, x);
    unsigned r = u + 0x7FFFu + ((u >> 16) & 1u);
    return (unsigned short)(r >> 16);
}
__device__ inline float bf16_to_f32(unsigned short h) {
    unsigned u = ((unsigned)h) << 16;
    return __builtin_bit_cast(float, u);
}
__device__ inline f32x4 ld_bf16x4(const unsigned short* p) {
    ushort4 u = *reinterpret_cast<const ushort4*>(p);
    f32x4 r;
    r[0] = bf16_to_f32(u.x); r[1] = bf16_to_f32(u.y);
    r[2] = bf16_to_f32(u.z); r[3] = bf16_to_f32(u.w);
    return r;
}
__device__ inline f32x4 max4(f32x4 a, f32x4 b) {
    f32x4 r;
#pragma unroll
    for (int j = 0; j < 4; ++j) r[j] = fmaxf(a[j], b[j]);
    return r;
}

// ---------------- CSR build ----------------

__global__ __launch_bounds__(256) void count_kernel(const int* __restrict__ dst,
                                                    int* __restrict__ indeg, int E) {
    int e = blockIdx.x * 256 + threadIdx.x;
    if (e < E) atomicAdd(&indeg[dst[e]], 1);
}

__global__ __launch_bounds__(256) void scanA(const int* __restrict__ in,
                                             int* __restrict__ out,
                                             int* __restrict__ bsum, int N) {
    __shared__ int tmp[256];
    int t = threadIdx.x;
    int g = blockIdx.x * 256 + t;
    int v = (g < N) ? in[g] : 0;
    tmp[t] = v;
    __syncthreads();
#pragma unroll
    for (int off = 1; off < 256; off <<= 1) {
        int add = (t >= off) ? tmp[t - off] : 0;
        __syncthreads();
        if (t >= off) tmp[t] += add;
        __syncthreads();
    }
    if (g < N) out[g] = tmp[t] - v;   // exclusive within block
    if (t == 255) bsum[blockIdx.x] = tmp[255];
}

__global__ __launch_bounds__(256) void scanB(int* __restrict__ bsum, int nb) {
    __shared__ int tmp[256];
    int t = threadIdx.x;
    int v = (t < nb) ? bsum[t] : 0;
    tmp[t] = v;
    __syncthreads();
#pragma unroll
    for (int off = 1; off < 256; off <<= 1) {
        int add = (t >= off) ? tmp[t - off] : 0;
        __syncthreads();
        if (t >= off) tmp[t] += add;
        __syncthreads();
    }
    if (t < nb) bsum[t] = tmp[t] - v;  // exclusive
}

__global__ __launch_bounds__(256) void scanC(int* __restrict__ rowstart,
                                             const int* __restrict__ bsum,
                                             int N, int E) {
    int g = blockIdx.x * 256 + threadIdx.x;
    if (g < N) rowstart[g] += bsum[blockIdx.x];
    if (g == 0) rowstart[N] = E;
}

__global__ __launch_bounds__(256) void dinv_kernel(const int* __restrict__ indeg,
                                                   float* __restrict__ dinv, int N) {
    int i = blockIdx.x * 256 + threadIdx.x;
    if (i < N) dinv[i] = rsqrtf((float)(indeg[i] + 1));  // +1 self loop
}

__global__ __launch_bounds__(256) void fill_csr(const int* __restrict__ src,
                                                const int* __restrict__ dst,
                                                const int* __restrict__ rowstart,
                                                int* __restrict__ fill,
                                                int* __restrict__ csr_src, int E) {
    int e = blockIdx.x * 256 + threadIdx.x;
    if (e < E) {
        int d = dst[e];
        int p = rowstart[d] + atomicAdd(&fill[d], 1);
        csr_src[p] = src[e];
    }
}

__global__ __launch_bounds__(256) void gstart_kernel(const int* __restrict__ batch,
                                                     int* __restrict__ gstart,
                                                     int N, int G) {
    int g = blockIdx.x * 256 + threadIdx.x;
    if (g > G) return;
    if (g == G) { gstart[G] = N; return; }
    int lo = 0, hi = N;
    while (lo < hi) {
        int mid = (lo + hi) >> 1;
        if (batch[mid] < g) lo = mid + 1; else hi = mid;
    }
    gstart[g] = lo;
}

// ---------------- weight pre-split: W[K][256] f32 -> packed bf16 hi/lo ------
// Wh/Wl layout: [K/32][256][32]  (k-tile, col, k-within) so GEMM B-staging is
// a coalesced linear copy per k-tile.
__global__ __launch_bounds__(256) void conv_w(const float* __restrict__ W,
                                              unsigned short* __restrict__ Wh,
                                              unsigned short* __restrict__ Wl,
                                              int K) {
    int idx = blockIdx.x * 256 + threadIdx.x;  // over K*256
    if (idx >= K * 256) return;
    int k = idx >> 8, c = idx & 255;
    float w = W[idx];
    unsigned short h = f32_to_bf16_rn(w);
    float lo = w - bf16_to_f32(h);
    unsigned short l = f32_to_bf16_rn(lo);
    size_t o = ((size_t)(k >> 5) * 256 + c) * 32 + (k & 31);
    Wh[o] = h;
    Wl[o] = l;
}

// ---------------- MFMA GEMM: out[row] = bf16((A[row] @ W) * scale[row]) -----
// A:[M,K] f32, W pre-split bf16 hi/lo packed [K/32][256][32], out:[M,256] bf16.
// bf16x3: (ah+al)(bh+bl) ~= ah*bh + al*bh + ah*bl  (residual ~2^-16 rel).
// Block: 64 rows x 256 cols, 4 waves; wave w owns cols [w*64, w*64+64).
// C/D map (verified m89/m91): col=lane&15, row=(lane>>4)*4+reg.
// A/B k-chunk permutation is self-cancelling (same bijection on both sides).
template <int K>
__global__ __launch_bounds__(256, 3) void gemm_mfma(const float* __restrict__ A,
                                                    const unsigned short* __restrict__ Bh,
                                                    const unsigned short* __restrict__ Bl,
                                                    const float* __restrict__ scale,
                                                    unsigned short* __restrict__ out, int M) {
    constexpr int LDT = 40;  // padded row (bf16 elems): 80 B -> ~2-way banks
    __shared__ __align__(16) unsigned short Ah[64 * LDT];
    __shared__ __align__(16) unsigned short Al[64 * LDT];
    __shared__ __align__(16) unsigned short BhT[256 * LDT];
    __shared__ __align__(16) unsigned short BlT[256 * LDT];

    const int tid  = threadIdx.x;
    const int lane = tid & 63;
    const int w    = tid >> 6;
    const int row0 = blockIdx.x * 64;
    const int q    = lane >> 4;
    const int r16  = lane & 15;

    f32x4 acc[4][4] = {};

    for (int k0 = 0; k0 < K; k0 += 32) {
        // ---- stage A tile (64 x 32 f32 -> hi/lo bf16) ----
        {
            int r = tid >> 2;
            int kq = (tid & 3) * 8;
            int grow = row0 + r;
            float4 v0 = make_float4(0.f, 0.f, 0.f, 0.f);
            float4 v1 = make_float4(0.f, 0.f, 0.f, 0.f);
            if (grow < M) {
                const float* ap = &A[(size_t)grow * K + k0 + kq];
                v0 = *reinterpret_cast<const float4*>(ap);
                v1 = *reinterpret_cast<const float4*>(ap + 4);
            }
            float xs[8] = {v0.x, v0.y, v0.z, v0.w, v1.x, v1.y, v1.z, v1.w};
            s16x8 hv, lv;
#pragma unroll
            for (int j = 0; j < 8; ++j) {
                unsigned short h = f32_to_bf16_rn(xs[j]);
                hv[j] = (short)h;
                lv[j] = (short)f32_to_bf16_rn(xs[j] - bf16_to_f32(h));
            }
            *reinterpret_cast<s16x8*>(&Ah[r * LDT + kq]) = hv;
            *reinterpret_cast<s16x8*>(&Al[r * LDT + kq]) = lv;
        }
        // ---- stage B tile (copy packed 256 x 32 bf16 hi/lo, coalesced) ----
        {
            size_t o = ((size_t)(k0 >> 5) * 256 + tid) * 32;
            const s16x8* bsh = reinterpret_cast<const s16x8*>(Bh + o);
            const s16x8* bsl = reinterpret_cast<const s16x8*>(Bl + o);
#pragma unroll
            for (int j = 0; j < 4; ++j) {
                *reinterpret_cast<s16x8*>(&BhT[tid * LDT + j * 8]) = bsh[j];
                *reinterpret_cast<s16x8*>(&BlT[tid * LDT + j * 8]) = bsl[j];
            }
        }
        __syncthreads();

        // ---- compute ----
        s16x8 bh[4], bl[4];
#pragma unroll
        for (int ct = 0; ct < 4; ++ct) {
            int col = w * 64 + ct * 16 + r16;
            bh[ct] = *reinterpret_cast<const s16x8*>(&BhT[col * LDT + q * 8]);
            bl[ct] = *reinterpret_cast<const s16x8*>(&BlT[col * LDT + q * 8]);
        }
#pragma unroll
        for (int rt = 0; rt < 4; ++rt) {
            int rr = rt * 16 + r16;
            s16x8 ah = *reinterpret_cast<const s16x8*>(&Ah[rr * LDT + q * 8]);
            s16x8 al = *reinterpret_cast<const s16x8*>(&Al[rr * LDT + q * 8]);
#pragma unroll
            for (int ct = 0; ct < 4; ++ct) {
                acc[rt][ct] = __builtin_amdgcn_mfma_f32_16x16x32_bf16(ah, bh[ct], acc[rt][ct], 0, 0, 0);
                acc[rt][ct] = __builtin_amdgcn_mfma_f32_16x16x32_bf16(al, bh[ct], acc[rt][ct], 0, 0, 0);
                acc[rt][ct] = __builtin_amdgcn_mfma_f32_16x16x32_bf16(ah, bl[ct], acc[rt][ct], 0, 0, 0);
            }
        }
        __syncthreads();
    }

    // ---- epilogue: scale by dinv[row], store bf16 ----
#pragma unroll
    for (int rt = 0; rt < 4; ++rt) {
#pragma unroll
        for (int i = 0; i < 4; ++i) {
            int grow = row0 + rt * 16 + q * 4 + i;
            if (grow < M) {
                float s = scale[grow];
#pragma unroll
                for (int ct = 0; ct < 4; ++ct) {
                    out[(size_t)grow * 256 + w * 64 + ct * 16 + r16] =
                        f32_to_bf16_rn(acc[rt][ct][i] * s);
                }
            }
        }
    }
}

// out[i] = maybe_relu(dinv[i] * (hs[i] + sum_{e: s->i} hs[s]) + bias)
// hs is bf16 [N][256] (512 B rows): one WAVE per node, lane gathers ushort4,
// accumulates f32. OUT_T=float (layer1, feeds GEMM2 hi/lo split) or
// ushort bf16 (layer2, feeds pool).
template <typename OUT_T>
__global__ __launch_bounds__(256) void agg_kernel(const unsigned short* __restrict__ hs,
                                                  const int* __restrict__ rowstart,
                                                  const int* __restrict__ csr_src,
                                                  const float* __restrict__ dinv,
                                                  const float* __restrict__ bias,
                                                  OUT_T* __restrict__ out,
                                                  int do_relu, int N) {
    int node = blockIdx.x * 4 + (threadIdx.x >> 6);
    if (node >= N) return;
    int lane = threadIdx.x & 63;

    f32x4 a0 = ld_bf16x4(hs + (size_t)node * 256 + lane * 4);
    f32x4 a1 = {}, a2 = {}, a3 = {};
    int e0 = rowstart[node], e1 = rowstart[node + 1];
    int e = e0;
    for (; e + 4 <= e1; e += 4) {
        int s0 = csr_src[e + 0];
        int s1 = csr_src[e + 1];
        int s2 = csr_src[e + 2];
        int s3 = csr_src[e + 3];
        a0 += ld_bf16x4(hs + (size_t)s0 * 256 + lane * 4);
        a1 += ld_bf16x4(hs + (size_t)s1 * 256 + lane * 4);
        a2 += ld_bf16x4(hs + (size_t)s2 * 256 + lane * 4);
        a3 += ld_bf16x4(hs + (size_t)s3 * 256 + lane * 4);
    }
    for (; e < e1; ++e) {
        a0 += ld_bf16x4(hs + (size_t)csr_src[e] * 256 + lane * 4);
    }
    f32x4 acc = (a0 + a1) + (a2 + a3);
    float dv = dinv[node];
    f32x4 b = *reinterpret_cast<const f32x4*>(bias + lane * 4);
    f32x4 v;
#pragma unroll
    for (int j = 0; j < 4; ++j) {
        float t = dv * acc[j] + b[j];
        v[j] = do_relu ? fmaxf(t, 0.f) : t;
    }
    if constexpr (sizeof(OUT_T) == 4) {
        *reinterpret_cast<f32x4*>(out + (size_t)node * 256 + lane * 4) = v;
    } else {
        ushort4 u;
        u.x = f32_to_bf16_rn(v[0]); u.y = f32_to_bf16_rn(v[1]);
        u.z = f32_to_bf16_rn(v[2]); u.w = f32_to_bf16_rn(v[3]);
        *reinterpret_cast<ushort4*>(out + (size_t)node * 256 + lane * 4) = u;
    }
}

// segment max over bf16 h rows: block per group; 4 waves split the rows;
// ushort4 lanes; 2 accumulators/wave; LDS reduce across waves. pooled f32.
__global__ __launch_bounds__(256) void pool_kernel(const unsigned short* __restrict__ h,
                                                   const int* __restrict__ gstart,
                                                   float* __restrict__ pooled) {
    __shared__ float red[4][256];
    int g = blockIdx.x;
    int w = threadIdx.x >> 6;
    int lane = threadIdx.x & 63;
    int i0 = gstart[g], i1 = gstart[g + 1];
    f32x4 m0 = {-INFINITY, -INFINITY, -INFINITY, -INFINITY};
    f32x4 m1 = m0;
    int i = i0 + w;
    for (; i + 4 < i1; i += 8) {
        m0 = max4(m0, ld_bf16x4(h + (size_t)i * 256 + lane * 4));
        m1 = max4(m1, ld_bf16x4(h + (size_t)(i + 4) * 256 + lane * 4));
    }
    if (i < i1) {
        m0 = max4(m0, ld_bf16x4(h + (size_t)i * 256 + lane * 4));
    }
    m0 = max4(m0, m1);
    *reinterpret_cast<f32x4*>(&red[w][lane * 4]) = m0;
    __syncthreads();
    int t = threadIdx.x;
    float mm = fmaxf(fmaxf(red[0][t], red[1][t]), fmaxf(red[2][t], red[3][t]));
    pooled[(size_t)g * 256 + t] = mm;
}

__global__ __launch_bounds__(256) void lsm_kernel(const float* __restrict__ pooled,
                                                  float* __restrict__ out) {
    __shared__ float red[256];
    int g = blockIdx.x, t = threadIdx.x;
    float v = pooled[(size_t)g * 256 + t];
    red[t] = v;
    __syncthreads();
#pragma unroll
    for (int off = 128; off > 0; off >>= 1) {
        if (t < off) red[t] = fmaxf(red[t], red[t + off]);
        __syncthreads();
    }
    float m = red[0];
    __syncthreads();
    red[t] = expf(v - m);
    __syncthreads();
#pragma unroll
    for (int off = 128; off > 0; off >>= 1) {
        if (t < off) red[t] += red[t + off];
        __syncthreads();
    }
    float s = red[0];
    out[(size_t)g * 256 + t] = v - m - logf(s);
}

extern "C" void kernel_launch(void* const* d_in, const int* in_sizes, int n_in,
                              void* d_out, int out_size, void* d_ws, size_t ws_size,
                              hipStream_t stream) {
    const float* x  = (const float*)d_in[0];
    const float* W1 = (const float*)d_in[1];
    const float* b1 = (const float*)d_in[2];
    const float* W2 = (const float*)d_in[3];
    const float* b2 = (const float*)d_in[4];
    const int* edge_index = (const int*)d_in[5];
    const int* batch = (const int*)d_in[6];
    float* out = (float*)d_out;

    const int N = in_sizes[6];
    const int E = in_sizes[5] / 2;
    const int H = in_sizes[2];        // 256
    const int G = out_size / H;       // 512
    const int K1 = in_sizes[1] / H;   // 128
    const int* src = edge_index;
    const int* dst = edge_index + E;

    // workspace layout
    char* p = (char*)d_ws;
    auto alloc = [&](size_t bytes) {
        char* r = p;
        p += (bytes + 255) & ~(size_t)255;
        return r;
    };
    int*   indeg    = (int*)alloc((size_t)N * 4);
    int*   rowstart = (int*)alloc((size_t)(N + 1) * 4);
    int*   fill     = (int*)alloc((size_t)N * 4);
    int*   bsum     = (int*)alloc(256 * 4);
    float* dinv     = (float*)alloc((size_t)N * 4);
    int*   gstart   = (int*)alloc((size_t)(G + 1) * 4);
    int*   csr_src  = (int*)alloc((size_t)E * 4);
    unsigned short* hsbuf = (unsigned short*)alloc((size_t)N * H * 2);  // GEMM out (bf16)
    float*          h1    = (float*)alloc((size_t)N * H * 4);           // layer1 out (f32)
    unsigned short* h2    = (unsigned short*)alloc((size_t)N * H * 2);  // layer2 out (bf16)
    float* pooled   = (float*)alloc((size_t)G * H * 4);
    unsigned short* w1h = (unsigned short*)alloc((size_t)K1 * H * 2);
    unsigned short* w1l = (unsigned short*)alloc((size_t)K1 * H * 2);
    unsigned short* w2h = (unsigned short*)alloc((size_t)H * H * 2);
    unsigned short* w2l = (unsigned short*)alloc((size_t)H * H * 2);

    hipMemsetAsync(indeg, 0, (size_t)N * 4, stream);
    hipMemsetAsync(fill, 0, (size_t)N * 4, stream);

    const int eb = (E + 255) / 256;
    const int nb = (N + 255) / 256;

    count_kernel<<<eb, 256, 0, stream>>>(dst, indeg, E);
    scanA<<<nb, 256, 0, stream>>>(indeg, rowstart, bsum, N);
    scanB<<<1, 256, 0, stream>>>(bsum, nb);
    scanC<<<nb, 256, 0, stream>>>(rowstart, bsum, N, E);
    dinv_kernel<<<nb, 256, 0, stream>>>(indeg, dinv, N);
    fill_csr<<<eb, 256, 0, stream>>>(src, dst, rowstart, fill, csr_src, E);
    gstart_kernel<<<(G + 1 + 255) / 256, 256, 0, stream>>>(batch, gstart, N, G);
    conv_w<<<(K1 * H + 255) / 256, 256, 0, stream>>>(W1, w1h, w1l, K1);
    conv_w<<<(H * H + 255) / 256, 256, 0, stream>>>(W2, w2h, w2l, H);

    const int gb = (N + 63) / 64;
    const int ab = (N + 3) / 4;
    // layer 1: hs = bf16((x @ W1) * dinv); h1 = relu(dinv*(gather+self)+b1) f32
    gemm_mfma<128><<<gb, 256, 0, stream>>>(x, w1h, w1l, dinv, hsbuf, N);
    agg_kernel<float><<<ab, 256, 0, stream>>>(hsbuf, rowstart, csr_src, dinv, b1, h1, 1, N);
    // layer 2: hs = bf16((h1 @ W2) * dinv); h2 = bf16(dinv*(gather+self)+b2)
    gemm_mfma<256><<<gb, 256, 0, stream>>>(h1, w2h, w2l, dinv, hsbuf, N);
    agg_kernel<unsigned short><<<ab, 256, 0, stream>>>(hsbuf, rowstart, csr_src, dinv, b2, h2, 0, N);
    // pooling + log_softmax
    pool_kernel<<<G, 256, 0, stream>>>(h2, gstart, pooled);
    lsm_kernel<<<G, 256, 0, stream>>>(pooled, out);
}

// Round 15
// 355.894 us; speedup vs baseline: 1.3931x; 1.0536x over previous
//
#include <hip/hip_runtime.h>
#include <hip/hip_bf16.h>

// ---------------------------------------------------------------------------
// GCN forward: 2x GCNConv (MFMA bf16 GEMM + bf16 CSR gather aggregation)
//              + fused segment_max/log_softmax
// r12 confirmed: random row-gather path saturates ~3.9 TB/s (49% HBM peak),
// time is byte-proportional. This round: h1 -> bf16 (halves agg1 write +
// GEMM2 A-read), fuse pool+lsm, fold dinv into scanC, merge conv_w, one memset.
// ---------------------------------------------------------------------------

typedef __attribute__((ext_vector_type(4))) float f32x4;
typedef __attribute__((ext_vector_type(8))) short s16x8;

__device__ inline unsigned short f32_to_bf16_rn(float x) {
    unsigned u = __builtin_bit_cast(unsigned, x);
    unsigned r = u + 0x7FFFu + ((u >> 16) & 1u);
    return (unsigned short)(r >> 16);
}
__device__ inline float bf16_to_f32(unsigned short h) {
    unsigned u = ((unsigned)h) << 16;
    return __builtin_bit_cast(float, u);
}
__device__ inline f32x4 ld_bf16x4(const unsigned short* p) {
    ushort4 u = *reinterpret_cast<const ushort4*>(p);
    f32x4 r;
    r[0] = bf16_to_f32(u.x); r[1] = bf16_to_f32(u.y);
    r[2] = bf16_to_f32(u.z); r[3] = bf16_to_f32(u.w);
    return r;
}
__device__ inline f32x4 max4(f32x4 a, f32x4 b) {
    f32x4 r;
#pragma unroll
    for (int j = 0; j < 4; ++j) r[j] = fmaxf(a[j], b[j]);
    return r;
}

// ---------------- CSR build ----------------

__global__ __launch_bounds__(256) void count_kernel(const int* __restrict__ dst,
                                                    int* __restrict__ indeg, int E) {
    int e = blockIdx.x * 256 + threadIdx.x;
    if (e < E) atomicAdd(&indeg[dst[e]], 1);
}

__global__ __launch_bounds__(256) void scanA(const int* __restrict__ in,
                                             int* __restrict__ out,
                                             int* __restrict__ bsum, int N) {
    __shared__ int tmp[256];
    int t = threadIdx.x;
    int g = blockIdx.x * 256 + t;
    int v = (g < N) ? in[g] : 0;
    tmp[t] = v;
    __syncthreads();
#pragma unroll
    for (int off = 1; off < 256; off <<= 1) {
        int add = (t >= off) ? tmp[t - off] : 0;
        __syncthreads();
        if (t >= off) tmp[t] += add;
        __syncthreads();
    }
    if (g < N) out[g] = tmp[t] - v;   // exclusive within block
    if (t == 255) bsum[blockIdx.x] = tmp[255];
}

__global__ __launch_bounds__(256) void scanB(int* __restrict__ bsum, int nb) {
    __shared__ int tmp[256];
    int t = threadIdx.x;
    int v = (t < nb) ? bsum[t] : 0;
    tmp[t] = v;
    __syncthreads();
#pragma unroll
    for (int off = 1; off < 256; off <<= 1) {
        int add = (t >= off) ? tmp[t - off] : 0;
        __syncthreads();
        if (t >= off) tmp[t] += add;
        __syncthreads();
    }
    if (t < nb) bsum[t] = tmp[t] - v;  // exclusive
}

// rowstart finalize + dinv (folded: same N-grid, indeg is final here)
__global__ __launch_bounds__(256) void scanC(int* __restrict__ rowstart,
                                             const int* __restrict__ bsum,
                                             const int* __restrict__ indeg,
                                             float* __restrict__ dinv,
                                             int N, int E) {
    int g = blockIdx.x * 256 + threadIdx.x;
    if (g < N) {
        rowstart[g] += bsum[blockIdx.x];
        dinv[g] = rsqrtf((float)(indeg[g] + 1));  // +1 self loop
    }
    if (g == 0) rowstart[N] = E;
}

__global__ __launch_bounds__(256) void fill_csr(const int* __restrict__ src,
                                                const int* __restrict__ dst,
                                                const int* __restrict__ rowstart,
                                                int* __restrict__ fill,
                                                int* __restrict__ csr_src, int E) {
    int e = blockIdx.x * 256 + threadIdx.x;
    if (e < E) {
        int d = dst[e];
        int p = rowstart[d] + atomicAdd(&fill[d], 1);
        csr_src[p] = src[e];
    }
}

__global__ __launch_bounds__(256) void gstart_kernel(const int* __restrict__ batch,
                                                     int* __restrict__ gstart,
                                                     int N, int G) {
    int g = blockIdx.x * 256 + threadIdx.x;
    if (g > G) return;
    if (g == G) { gstart[G] = N; return; }
    int lo = 0, hi = N;
    while (lo < hi) {
        int mid = (lo + hi) >> 1;
        if (batch[mid] < g) lo = mid + 1; else hi = mid;
    }
    gstart[g] = lo;
}

// ---------------- weight pre-split (both layers, one launch) ----------------
// W[K][256] f32 -> packed bf16 hi/lo, layout [K/32][256][32].
__global__ __launch_bounds__(256) void conv_w2(const float* __restrict__ Wa, int Ka,
                                               unsigned short* __restrict__ Wah,
                                               unsigned short* __restrict__ Wal,
                                               const float* __restrict__ Wb, int Kb,
                                               unsigned short* __restrict__ Wbh,
                                               unsigned short* __restrict__ Wbl) {
    int idx = blockIdx.x * 256 + threadIdx.x;
    const float* W;
    unsigned short *Wh, *Wl;
    if (idx < Ka * 256) {
        W = Wa; Wh = Wah; Wl = Wal;
    } else {
        idx -= Ka * 256;
        if (idx >= Kb * 256) return;
        W = Wb; Wh = Wbh; Wl = Wbl;
    }
    int k = idx >> 8, c = idx & 255;
    float w = W[idx];
    unsigned short h = f32_to_bf16_rn(w);
    float lo = w - bf16_to_f32(h);
    size_t o = ((size_t)(k >> 5) * 256 + c) * 32 + (k & 31);
    Wh[o] = h;
    Wl[o] = f32_to_bf16_rn(lo);
}

// ---------------- MFMA GEMM: out[row] = bf16((A[row] @ W) * scale[row]) -----
// AT=float: A split hi/lo on the fly, 3 MFMA/tile (bf16x3).
// AT=ushort (bf16): A loaded directly, hi-term only, 2 MFMA/tile.
// W pre-split bf16 hi/lo packed [K/32][256][32]; out [M,256] bf16.
// Block 64 rows x 256 cols, 4 waves; wave w owns cols [w*64, w*64+64).
// C/D map (verified m89/m91): col=lane&15, row=(lane>>4)*4+reg.
template <int K, typename AT>
__global__ __launch_bounds__(256, 3) void gemm_mfma(const AT* __restrict__ A,
                                                    const unsigned short* __restrict__ Bh,
                                                    const unsigned short* __restrict__ Bl,
                                                    const float* __restrict__ scale,
                                                    unsigned short* __restrict__ out, int M) {
    constexpr int LDT = 40;  // padded row (bf16 elems): 80 B -> ~2-way banks
    __shared__ __align__(16) unsigned short Ah[64 * LDT];
    __shared__ __align__(16) unsigned short Al[64 * LDT];   // unused for AT=bf16
    __shared__ __align__(16) unsigned short BhT[256 * LDT];
    __shared__ __align__(16) unsigned short BlT[256 * LDT];

    const int tid  = threadIdx.x;
    const int lane = tid & 63;
    const int w    = tid >> 6;
    const int row0 = blockIdx.x * 64;
    const int q    = lane >> 4;
    const int r16  = lane & 15;

    f32x4 acc[4][4] = {};

    for (int k0 = 0; k0 < K; k0 += 32) {
        // ---- stage A tile (64 x 32) ----
        {
            int r = tid >> 2;          // 64 rows, 4 threads/row
            int kq = (tid & 3) * 8;    // 8 elems each
            int grow = row0 + r;
            if constexpr (sizeof(AT) == 4) {
                float4 v0 = make_float4(0.f, 0.f, 0.f, 0.f);
                float4 v1 = make_float4(0.f, 0.f, 0.f, 0.f);
                if (grow < M) {
                    const float* ap = &A[(size_t)grow * K + k0 + kq];
                    v0 = *reinterpret_cast<const float4*>(ap);
                    v1 = *reinterpret_cast<const float4*>(ap + 4);
                }
                float xs[8] = {v0.x, v0.y, v0.z, v0.w, v1.x, v1.y, v1.z, v1.w};
                s16x8 hv, lv;
#pragma unroll
                for (int j = 0; j < 8; ++j) {
                    unsigned short h = f32_to_bf16_rn(xs[j]);
                    hv[j] = (short)h;
                    lv[j] = (short)f32_to_bf16_rn(xs[j] - bf16_to_f32(h));
                }
                *reinterpret_cast<s16x8*>(&Ah[r * LDT + kq]) = hv;
                *reinterpret_cast<s16x8*>(&Al[r * LDT + kq]) = lv;
            } else {
                s16x8 hv = {};
                if (grow < M)
                    hv = *reinterpret_cast<const s16x8*>(&A[(size_t)grow * K + k0 + kq]);
                *reinterpret_cast<s16x8*>(&Ah[r * LDT + kq]) = hv;
            }
        }
        // ---- stage B tile (copy packed 256 x 32 bf16 hi/lo, coalesced) ----
        {
            size_t o = ((size_t)(k0 >> 5) * 256 + tid) * 32;
            const s16x8* bsh = reinterpret_cast<const s16x8*>(Bh + o);
            const s16x8* bsl = reinterpret_cast<const s16x8*>(Bl + o);
#pragma unroll
            for (int j = 0; j < 4; ++j) {
                *reinterpret_cast<s16x8*>(&BhT[tid * LDT + j * 8]) = bsh[j];
                *reinterpret_cast<s16x8*>(&BlT[tid * LDT + j * 8]) = bsl[j];
            }
        }
        __syncthreads();

        // ---- compute ----
        s16x8 bh[4], bl[4];
#pragma unroll
        for (int ct = 0; ct < 4; ++ct) {
            int col = w * 64 + ct * 16 + r16;
            bh[ct] = *reinterpret_cast<const s16x8*>(&BhT[col * LDT + q * 8]);
            bl[ct] = *reinterpret_cast<const s16x8*>(&BlT[col * LDT + q * 8]);
        }
#pragma unroll
        for (int rt = 0; rt < 4; ++rt) {
            int rr = rt * 16 + r16;
            s16x8 ah = *reinterpret_cast<const s16x8*>(&Ah[rr * LDT + q * 8]);
            if constexpr (sizeof(AT) == 4) {
                s16x8 al = *reinterpret_cast<const s16x8*>(&Al[rr * LDT + q * 8]);
#pragma unroll
                for (int ct = 0; ct < 4; ++ct) {
                    acc[rt][ct] = __builtin_amdgcn_mfma_f32_16x16x32_bf16(ah, bh[ct], acc[rt][ct], 0, 0, 0);
                    acc[rt][ct] = __builtin_amdgcn_mfma_f32_16x16x32_bf16(al, bh[ct], acc[rt][ct], 0, 0, 0);
                    acc[rt][ct] = __builtin_amdgcn_mfma_f32_16x16x32_bf16(ah, bl[ct], acc[rt][ct], 0, 0, 0);
                }
            } else {
#pragma unroll
                for (int ct = 0; ct < 4; ++ct) {
                    acc[rt][ct] = __builtin_amdgcn_mfma_f32_16x16x32_bf16(ah, bh[ct], acc[rt][ct], 0, 0, 0);
                    acc[rt][ct] = __builtin_amdgcn_mfma_f32_16x16x32_bf16(ah, bl[ct], acc[rt][ct], 0, 0, 0);
                }
            }
        }
        __syncthreads();
    }

    // ---- epilogue: scale by dinv[row], store bf16 ----
#pragma unroll
    for (int rt = 0; rt < 4; ++rt) {
#pragma unroll
        for (int i = 0; i < 4; ++i) {
            int grow = row0 + rt * 16 + q * 4 + i;
            if (grow < M) {
                float s = scale[grow];
#pragma unroll
                for (int ct = 0; ct < 4; ++ct) {
                    out[(size_t)grow * 256 + w * 64 + ct * 16 + r16] =
                        f32_to_bf16_rn(acc[rt][ct][i] * s);
                }
            }
        }
    }
}

// out[i] = bf16(maybe_relu(dinv[i] * (hs[i] + sum_e hs[src]) + bias))
// hs bf16 [N][256] (512 B rows): one wave per node, ushort4/lane, f32 accum.
__global__ __launch_bounds__(256) void agg_kernel(const unsigned short* __restrict__ hs,
                                                  const int* __restrict__ rowstart,
                                                  const int* __restrict__ csr_src,
                                                  const float* __restrict__ dinv,
                                                  const float* __restrict__ bias,
                                                  unsigned short* __restrict__ out,
                                                  int do_relu, int N) {
    int node = blockIdx.x * 4 + (threadIdx.x >> 6);
    if (node >= N) return;
    int lane = threadIdx.x & 63;

    f32x4 a0 = ld_bf16x4(hs + (size_t)node * 256 + lane * 4);
    f32x4 a1 = {}, a2 = {}, a3 = {};
    int e0 = rowstart[node], e1 = rowstart[node + 1];
    int e = e0;
    for (; e + 4 <= e1; e += 4) {
        int s0 = csr_src[e + 0];
        int s1 = csr_src[e + 1];
        int s2 = csr_src[e + 2];
        int s3 = csr_src[e + 3];
        a0 += ld_bf16x4(hs + (size_t)s0 * 256 + lane * 4);
        a1 += ld_bf16x4(hs + (size_t)s1 * 256 + lane * 4);
        a2 += ld_bf16x4(hs + (size_t)s2 * 256 + lane * 4);
        a3 += ld_bf16x4(hs + (size_t)s3 * 256 + lane * 4);
    }
    for (; e < e1; ++e) {
        a0 += ld_bf16x4(hs + (size_t)csr_src[e] * 256 + lane * 4);
    }
    f32x4 acc = (a0 + a1) + (a2 + a3);
    float dv = dinv[node];
    f32x4 b = *reinterpret_cast<const f32x4*>(bias + lane * 4);
    ushort4 u;
#pragma unroll
    for (int j = 0; j < 4; ++j) {
        float t = dv * acc[j] + b[j];
        if (do_relu) t = fmaxf(t, 0.f);
        (&u.x)[j] = f32_to_bf16_rn(t);
    }
    *reinterpret_cast<ushort4*>(out + (size_t)node * 256 + lane * 4) = u;
}

// fused segment-max + log_softmax: block per group; 4 waves split rows
// (ushort4 lanes, 2 accumulators); LDS reduce -> pooled row lives across the
// 256 threads -> block-wide max/sum-exp -> write final logits directly.
__global__ __launch_bounds__(256) void pool_lsm_kernel(const unsigned short* __restrict__ h,
                                                       const int* __restrict__ gstart,
                                                       float* __restrict__ out) {
    __shared__ float red[4][256];
    __shared__ float red2[256];
    int g = blockIdx.x;
    int w = threadIdx.x >> 6;
    int lane = threadIdx.x & 63;
    int i0 = gstart[g], i1 = gstart[g + 1];
    f32x4 m0 = {-INFINITY, -INFINITY, -INFINITY, -INFINITY};
    f32x4 m1 = m0;
    int i = i0 + w;
    for (; i + 4 < i1; i += 8) {
        m0 = max4(m0, ld_bf16x4(h + (size_t)i * 256 + lane * 4));
        m1 = max4(m1, ld_bf16x4(h + (size_t)(i + 4) * 256 + lane * 4));
    }
    if (i < i1) {
        m0 = max4(m0, ld_bf16x4(h + (size_t)i * 256 + lane * 4));
    }
    m0 = max4(m0, m1);
    *reinterpret_cast<f32x4*>(&red[w][lane * 4]) = m0;
    __syncthreads();
    int t = threadIdx.x;
    float v = fmaxf(fmaxf(red[0][t], red[1][t]), fmaxf(red[2][t], red[3][t]));
    // log_softmax across the 256 columns (one per thread)
    red2[t] = v;
    __syncthreads();
#pragma unroll
    for (int off = 128; off > 0; off >>= 1) {
        if (t < off) red2[t] = fmaxf(red2[t], red2[t + off]);
        __syncthreads();
    }
    float m = red2[0];
    __syncthreads();
    red2[t] = expf(v - m);
    __syncthreads();
#pragma unroll
    for (int off = 128; off > 0; off >>= 1) {
        if (t < off) red2[t] += red2[t + off];
        __syncthreads();
    }
    float s = red2[0];
    out[(size_t)g * 256 + t] = v - m - logf(s);
}

extern "C" void kernel_launch(void* const* d_in, const int* in_sizes, int n_in,
                              void* d_out, int out_size, void* d_ws, size_t ws_size,
                              hipStream_t stream) {
    const float* x  = (const float*)d_in[0];
    const float* W1 = (const float*)d_in[1];
    const float* b1 = (const float*)d_in[2];
    const float* W2 = (const float*)d_in[3];
    const float* b2 = (const float*)d_in[4];
    const int* edge_index = (const int*)d_in[5];
    const int* batch = (const int*)d_in[6];
    float* out = (float*)d_out;

    const int N = in_sizes[6];
    const int E = in_sizes[5] / 2;
    const int H = in_sizes[2];        // 256
    const int G = out_size / H;       // 512
    const int K1 = in_sizes[1] / H;   // 128
    const int* src = edge_index;
    const int* dst = edge_index + E;

    // workspace layout (indeg and fill adjacent -> one memset covers both)
    char* p = (char*)d_ws;
    auto alloc = [&](size_t bytes) {
        char* r = p;
        p += (bytes + 255) & ~(size_t)255;
        return r;
    };
    int*   indeg    = (int*)alloc((size_t)N * 4);
    int*   fill     = (int*)alloc((size_t)N * 4);
    int*   rowstart = (int*)alloc((size_t)(N + 1) * 4);
    int*   bsum     = (int*)alloc(256 * 4);
    float* dinv     = (float*)alloc((size_t)N * 4);
    int*   gstart   = (int*)alloc((size_t)(G + 1) * 4);
    int*   csr_src  = (int*)alloc((size_t)E * 4);
    unsigned short* hsbuf = (unsigned short*)alloc((size_t)N * H * 2);  // GEMM out (bf16)
    unsigned short* h1    = (unsigned short*)alloc((size_t)N * H * 2);  // layer1 out (bf16)
    unsigned short* h2    = (unsigned short*)alloc((size_t)N * H * 2);  // layer2 out (bf16)
    unsigned short* w1h = (unsigned short*)alloc((size_t)K1 * H * 2);
    unsigned short* w1l = (unsigned short*)alloc((size_t)K1 * H * 2);
    unsigned short* w2h = (unsigned short*)alloc((size_t)H * H * 2);
    unsigned short* w2l = (unsigned short*)alloc((size_t)H * H * 2);

    // zero indeg+fill in one shot (they are adjacent; pad bytes harmless)
    size_t zspan = (size_t)((char*)(fill + N) - (char*)indeg);
    hipMemsetAsync(indeg, 0, zspan, stream);

    const int eb = (E + 255) / 256;
    const int nb = (N + 255) / 256;

    count_kernel<<<eb, 256, 0, stream>>>(dst, indeg, E);
    scanA<<<nb, 256, 0, stream>>>(indeg, rowstart, bsum, N);
    scanB<<<1, 256, 0, stream>>>(bsum, nb);
    scanC<<<nb, 256, 0, stream>>>(rowstart, bsum, indeg, dinv, N, E);
    fill_csr<<<eb, 256, 0, stream>>>(src, dst, rowstart, fill, csr_src, E);
    gstart_kernel<<<(G + 1 + 255) / 256, 256, 0, stream>>>(batch, gstart, N, G);
    conv_w2<<<((K1 + H) * H + 255) / 256, 256, 0, stream>>>(W1, K1, w1h, w1l,
                                                            W2, H, w2h, w2l);

    const int gb = (N + 63) / 64;
    const int ab = (N + 3) / 4;
    // layer 1: hs = bf16((x @ W1) * dinv); h1 = bf16(relu(dinv*(gather+self)+b1))
    gemm_mfma<128, float><<<gb, 256, 0, stream>>>(x, w1h, w1l, dinv, hsbuf, N);
    agg_kernel<<<ab, 256, 0, stream>>>(hsbuf, rowstart, csr_src, dinv, b1, h1, 1, N);
    // layer 2: hs = bf16((h1 @ W2) * dinv); h2 = bf16(dinv*(gather+self)+b2)
    gemm_mfma<256, unsigned short><<<gb, 256, 0, stream>>>(h1, w2h, w2l, dinv, hsbuf, N);
    agg_kernel<<<ab, 256, 0, stream>>>(hsbuf, rowstart, csr_src, dinv, b2, h2, 0, N);
    // fused pooling + log_softmax
    pool_lsm_kernel<<<G, 256, 0, stream>>>(h2, gstart, out);
}

// Round 17
// 339.471 us; speedup vs baseline: 1.4605x; 1.0484x over previous
//
#include <hip/hip_runtime.h>
#include <hip/hip_bf16.h>

// ---------------------------------------------------------------------------
// GCN forward, aggregate-first layer 1:
//   xb = bf16(x * dinv)               [N,128]
//   y  = bf16(dinv * gather(xb))      [N,128]   (A(X W) == (A X) W commute)
//   h1 = bf16(relu(y @ W1 + b1))      [N,256]   (GEMM epilogue bias+relu)
//   hs = bf16((h1 @ W2) * dinv)       [N,256]
//   h2 = bf16(dinv * gather(hs) + b2) [N,256]
//   out = log_softmax(segment_max(h2))
// r12/r15: random gather FETCH == 8 XCD x buffer size (compulsory), path
// saturates ~3.6-3.9 TB/s -> only lever is fewer gathered bytes. Layer-1
// gather moves from 512B rows (hs) to 256B rows (xb).
// ---------------------------------------------------------------------------

typedef __attribute__((ext_vector_type(4))) float f32x4;
typedef __attribute__((ext_vector_type(8))) short s16x8;

__device__ inline unsigned short f32_to_bf16_rn(float x) {
    unsigned u = __builtin_bit_cast(unsigned, x);
    unsigned r = u + 0x7FFFu + ((u >> 16) & 1u);
    return (unsigned short)(r >> 16);
}
__device__ inline float bf16_to_f32(unsigned short h) {
    unsigned u = ((unsigned)h) << 16;
    return __builtin_bit_cast(float, u);
}
__device__ inline f32x4 ld_bf16x4(const unsigned short* p) {
    ushort4 u = *reinterpret_cast<const ushort4*>(p);
    f32x4 r;
    r[0] = bf16_to_f32(u.x); r[1] = bf16_to_f32(u.y);
    r[2] = bf16_to_f32(u.z); r[3] = bf16_to_f32(u.w);
    return r;
}
__device__ inline f32x4 max4(f32x4 a, f32x4 b) {
    f32x4 r;
#pragma unroll
    for (int j = 0; j < 4; ++j) r[j] = fmaxf(a[j], b[j]);
    return r;
}

// ---------------- CSR build ----------------

__global__ __launch_bounds__(256) void count_kernel(const int* __restrict__ dst,
                                                    int* __restrict__ indeg, int E) {
    int e = blockIdx.x * 256 + threadIdx.x;
    if (e < E) atomicAdd(&indeg[dst[e]], 1);
}

__global__ __launch_bounds__(256) void scanA(const int* __restrict__ in,
                                             int* __restrict__ out,
                                             int* __restrict__ bsum, int N) {
    __shared__ int tmp[256];
    int t = threadIdx.x;
    int g = blockIdx.x * 256 + t;
    int v = (g < N) ? in[g] : 0;
    tmp[t] = v;
    __syncthreads();
#pragma unroll
    for (int off = 1; off < 256; off <<= 1) {
        int add = (t >= off) ? tmp[t - off] : 0;
        __syncthreads();
        if (t >= off) tmp[t] += add;
        __syncthreads();
    }
    if (g < N) out[g] = tmp[t] - v;   // exclusive within block
    if (t == 255) bsum[blockIdx.x] = tmp[255];
}

__global__ __launch_bounds__(256) void scanB(int* __restrict__ bsum, int nb) {
    __shared__ int tmp[256];
    int t = threadIdx.x;
    int v = (t < nb) ? bsum[t] : 0;
    tmp[t] = v;
    __syncthreads();
#pragma unroll
    for (int off = 1; off < 256; off <<= 1) {
        int add = (t >= off) ? tmp[t - off] : 0;
        __syncthreads();
        if (t >= off) tmp[t] += add;
        __syncthreads();
    }
    if (t < nb) bsum[t] = tmp[t] - v;  // exclusive
}

// rowstart finalize + dinv (folded)
__global__ __launch_bounds__(256) void scanC(int* __restrict__ rowstart,
                                             const int* __restrict__ bsum,
                                             const int* __restrict__ indeg,
                                             float* __restrict__ dinv,
                                             int N, int E) {
    int g = blockIdx.x * 256 + threadIdx.x;
    if (g < N) {
        rowstart[g] += bsum[blockIdx.x];
        dinv[g] = rsqrtf((float)(indeg[g] + 1));  // +1 self loop
    }
    if (g == 0) rowstart[N] = E;
}

__global__ __launch_bounds__(256) void fill_csr(const int* __restrict__ src,
                                                const int* __restrict__ dst,
                                                const int* __restrict__ rowstart,
                                                int* __restrict__ fill,
                                                int* __restrict__ csr_src, int E) {
    int e = blockIdx.x * 256 + threadIdx.x;
    if (e < E) {
        int d = dst[e];
        int p = rowstart[d] + atomicAdd(&fill[d], 1);
        csr_src[p] = src[e];
    }
}

__global__ __launch_bounds__(256) void gstart_kernel(const int* __restrict__ batch,
                                                     int* __restrict__ gstart,
                                                     int N, int G) {
    int g = blockIdx.x * 256 + threadIdx.x;
    if (g > G) return;
    if (g == G) { gstart[G] = N; return; }
    int lo = 0, hi = N;
    while (lo < hi) {
        int mid = (lo + hi) >> 1;
        if (batch[mid] < g) lo = mid + 1; else hi = mid;
    }
    gstart[g] = lo;
}

// ---------------- weight pre-split (both layers, one launch) ----------------
// W[K][256] f32 -> packed bf16 hi/lo, layout [K/32][256][32].
__global__ __launch_bounds__(256) void conv_w2(const float* __restrict__ Wa, int Ka,
                                               unsigned short* __restrict__ Wah,
                                               unsigned short* __restrict__ Wal,
                                               const float* __restrict__ Wb, int Kb,
                                               unsigned short* __restrict__ Wbh,
                                               unsigned short* __restrict__ Wbl) {
    int idx = blockIdx.x * 256 + threadIdx.x;
    const float* W;
    unsigned short *Wh, *Wl;
    if (idx < Ka * 256) {
        W = Wa; Wh = Wah; Wl = Wal;
    } else {
        idx -= Ka * 256;
        if (idx >= Kb * 256) return;
        W = Wb; Wh = Wbh; Wl = Wbl;
    }
    int k = idx >> 8, c = idx & 255;
    float w = W[idx];
    unsigned short h = f32_to_bf16_rn(w);
    float lo = w - bf16_to_f32(h);
    size_t o = ((size_t)(k >> 5) * 256 + c) * 32 + (k & 31);
    Wh[o] = h;
    Wl[o] = f32_to_bf16_rn(lo);
}

// ---------------- cast+scale: xb = bf16(x * dinv[row]), row-major [N,128] ---
__global__ __launch_bounds__(256) void cast_scale(const float* __restrict__ x,
                                                  const float* __restrict__ dinv,
                                                  unsigned short* __restrict__ xb,
                                                  int total4) {  // total4 = N*128/4
    int idx = blockIdx.x * 256 + threadIdx.x;
    if (idx >= total4) return;
    int base = idx * 4;
    float4 v = *reinterpret_cast<const float4*>(x + base);
    float dv = dinv[base >> 7];  // 128 elems/row, 4-aligned -> same row
    ushort4 u;
    u.x = f32_to_bf16_rn(v.x * dv);
    u.y = f32_to_bf16_rn(v.y * dv);
    u.z = f32_to_bf16_rn(v.z * dv);
    u.w = f32_to_bf16_rn(v.w * dv);
    *reinterpret_cast<ushort4*>(xb + base) = u;
}

// ---------------- MFMA GEMM, bf16 A: out = bf16(epi(A @ W)) -----------------
// EPI=0: out = (acc) * scale[row]          (layer-2: * dinv)
// EPI=1: out = relu(acc + bias[col])       (layer-1: + b1, relu)
// W pre-split bf16 hi/lo packed [K/32][256][32]; A bf16 [M,K]; out [M,256] bf16.
// Block 64 rows x 256 cols, 4 waves; wave w owns cols [w*64, w*64+64).
// C/D map (verified m89/m91): col=lane&15, row=(lane>>4)*4+reg.
template <int K, int EPI>
__global__ __launch_bounds__(256, 3) void gemm_mfma(const unsigned short* __restrict__ A,
                                                    const unsigned short* __restrict__ Bh,
                                                    const unsigned short* __restrict__ Bl,
                                                    const float* __restrict__ scale,
                                                    const float* __restrict__ bias,
                                                    unsigned short* __restrict__ out, int M) {
    constexpr int LDT = 40;  // padded row (bf16 elems): 80 B -> ~2-way banks
    __shared__ __align__(16) unsigned short Ah[64 * LDT];
    __shared__ __align__(16) unsigned short BhT[256 * LDT];
    __shared__ __align__(16) unsigned short BlT[256 * LDT];

    const int tid  = threadIdx.x;
    const int lane = tid & 63;
    const int w    = tid >> 6;
    const int row0 = blockIdx.x * 64;
    const int q    = lane >> 4;
    const int r16  = lane & 15;

    f32x4 acc[4][4] = {};

    for (int k0 = 0; k0 < K; k0 += 32) {
        // ---- stage A tile (64 x 32 bf16) ----
        {
            int r = tid >> 2;          // 64 rows, 4 threads/row
            int kq = (tid & 3) * 8;    // 8 elems each
            int grow = row0 + r;
            s16x8 hv = {};
            if (grow < M)
                hv = *reinterpret_cast<const s16x8*>(&A[(size_t)grow * K + k0 + kq]);
            *reinterpret_cast<s16x8*>(&Ah[r * LDT + kq]) = hv;
        }
        // ---- stage B tile (copy packed 256 x 32 bf16 hi/lo, coalesced) ----
        {
            size_t o = ((size_t)(k0 >> 5) * 256 + tid) * 32;
            const s16x8* bsh = reinterpret_cast<const s16x8*>(Bh + o);
            const s16x8* bsl = reinterpret_cast<const s16x8*>(Bl + o);
#pragma unroll
            for (int j = 0; j < 4; ++j) {
                *reinterpret_cast<s16x8*>(&BhT[tid * LDT + j * 8]) = bsh[j];
                *reinterpret_cast<s16x8*>(&BlT[tid * LDT + j * 8]) = bsl[j];
            }
        }
        __syncthreads();

        // ---- compute: A(bf16) x (Wh + Wl) -> 2 MFMA per tile ----
        s16x8 bh[4], bl[4];
#pragma unroll
        for (int ct = 0; ct < 4; ++ct) {
            int col = w * 64 + ct * 16 + r16;
            bh[ct] = *reinterpret_cast<const s16x8*>(&BhT[col * LDT + q * 8]);
            bl[ct] = *reinterpret_cast<const s16x8*>(&BlT[col * LDT + q * 8]);
        }
#pragma unroll
        for (int rt = 0; rt < 4; ++rt) {
            int rr = rt * 16 + r16;
            s16x8 ah = *reinterpret_cast<const s16x8*>(&Ah[rr * LDT + q * 8]);
#pragma unroll
            for (int ct = 0; ct < 4; ++ct) {
                acc[rt][ct] = __builtin_amdgcn_mfma_f32_16x16x32_bf16(ah, bh[ct], acc[rt][ct], 0, 0, 0);
                acc[rt][ct] = __builtin_amdgcn_mfma_f32_16x16x32_bf16(ah, bl[ct], acc[rt][ct], 0, 0, 0);
            }
        }
        __syncthreads();
    }

    // ---- epilogue ----
    if constexpr (EPI == 1) {
        float bcol[4];
#pragma unroll
        for (int ct = 0; ct < 4; ++ct) bcol[ct] = bias[w * 64 + ct * 16 + r16];
#pragma unroll
        for (int rt = 0; rt < 4; ++rt) {
#pragma unroll
            for (int i = 0; i < 4; ++i) {
                int grow = row0 + rt * 16 + q * 4 + i;
                if (grow < M) {
#pragma unroll
                    for (int ct = 0; ct < 4; ++ct) {
                        float t = acc[rt][ct][i] + bcol[ct];
                        out[(size_t)grow * 256 + w * 64 + ct * 16 + r16] =
                            f32_to_bf16_rn(fmaxf(t, 0.f));
                    }
                }
            }
        }
    } else {
#pragma unroll
        for (int rt = 0; rt < 4; ++rt) {
#pragma unroll
            for (int i = 0; i < 4; ++i) {
                int grow = row0 + rt * 16 + q * 4 + i;
                if (grow < M) {
                    float s = scale[grow];
#pragma unroll
                    for (int ct = 0; ct < 4; ++ct) {
                        out[(size_t)grow * 256 + w * 64 + ct * 16 + r16] =
                            f32_to_bf16_rn(acc[rt][ct][i] * s);
                    }
                }
            }
        }
    }
}

// ---------------- gather-aggregate over D = VE*64 dims ----------------------
// out[i] = bf16(dinv[i]*(hs[i] + sum_e hs[src]) [+ bias])   (bias nullable)
// One wave per node; lane handles VE bf16; f32 accum; 4-way edge unroll.
template <int VE>
__global__ __launch_bounds__(256) void agg_kernel(const unsigned short* __restrict__ hs,
                                                  const int* __restrict__ rowstart,
                                                  const int* __restrict__ csr_src,
                                                  const float* __restrict__ dinv,
                                                  const float* __restrict__ bias,
                                                  unsigned short* __restrict__ out,
                                                  int N) {
    constexpr int D = VE * 64;
    int node = blockIdx.x * 4 + (threadIdx.x >> 6);
    if (node >= N) return;
    int lane = threadIdx.x & 63;
    const int lo = lane * VE;

    float a0[VE], a1[VE] = {}, a2[VE] = {}, a3[VE] = {};
    {
        const unsigned short* p = hs + (size_t)node * D + lo;
#pragma unroll
        for (int j = 0; j < VE; ++j) a0[j] = bf16_to_f32(p[j]);
    }
    int e0 = rowstart[node], e1 = rowstart[node + 1];
    int e = e0;
    for (; e + 4 <= e1; e += 4) {
        const unsigned short* p0 = hs + (size_t)csr_src[e + 0] * D + lo;
        const unsigned short* p1 = hs + (size_t)csr_src[e + 1] * D + lo;
        const unsigned short* p2 = hs + (size_t)csr_src[e + 2] * D + lo;
        const unsigned short* p3 = hs + (size_t)csr_src[e + 3] * D + lo;
#pragma unroll
        for (int j = 0; j < VE; ++j) {
            a0[j] += bf16_to_f32(p0[j]);
            a1[j] += bf16_to_f32(p1[j]);
            a2[j] += bf16_to_f32(p2[j]);
            a3[j] += bf16_to_f32(p3[j]);
        }
    }
    for (; e < e1; ++e) {
        const unsigned short* p = hs + (size_t)csr_src[e] * D + lo;
#pragma unroll
        for (int j = 0; j < VE; ++j) a0[j] += bf16_to_f32(p[j]);
    }
    float dv = dinv[node];
    unsigned short u[VE];
#pragma unroll
    for (int j = 0; j < VE; ++j) {
        float t = dv * ((a0[j] + a1[j]) + (a2[j] + a3[j]));
        if (bias) t += bias[lo + j];
        u[j] = f32_to_bf16_rn(t);
    }
    if constexpr (VE == 2) {
        *reinterpret_cast<ushort2*>(out + (size_t)node * D + lo) = *reinterpret_cast<ushort2*>(u);
    } else {
        *reinterpret_cast<ushort4*>(out + (size_t)node * D + lo) = *reinterpret_cast<ushort4*>(u);
    }
}

// fused segment-max + log_softmax
__global__ __launch_bounds__(256) void pool_lsm_kernel(const unsigned short* __restrict__ h,
                                                       const int* __restrict__ gstart,
                                                       float* __restrict__ out) {
    __shared__ float red[4][256];
    __shared__ float red2[256];
    int g = blockIdx.x;
    int w = threadIdx.x >> 6;
    int lane = threadIdx.x & 63;
    int i0 = gstart[g], i1 = gstart[g + 1];
    f32x4 m0 = {-INFINITY, -INFINITY, -INFINITY, -INFINITY};
    f32x4 m1 = m0;
    int i = i0 + w;
    for (; i + 4 < i1; i += 8) {
        m0 = max4(m0, ld_bf16x4(h + (size_t)i * 256 + lane * 4));
        m1 = max4(m1, ld_bf16x4(h + (size_t)(i + 4) * 256 + lane * 4));
    }
    if (i < i1) {
        m0 = max4(m0, ld_bf16x4(h + (size_t)i * 256 + lane * 4));
    }
    m0 = max4(m0, m1);
    *reinterpret_cast<f32x4*>(&red[w][lane * 4]) = m0;
    __syncthreads();
    int t = threadIdx.x;
    float v = fmaxf(fmaxf(red[0][t], red[1][t]), fmaxf(red[2][t], red[3][t]));
    red2[t] = v;
    __syncthreads();
#pragma unroll
    for (int off = 128; off > 0; off >>= 1) {
        if (t < off) red2[t] = fmaxf(red2[t], red2[t + off]);
        __syncthreads();
    }
    float m = red2[0];
    __syncthreads();
    red2[t] = expf(v - m);
    __syncthreads();
#pragma unroll
    for (int off = 128; off > 0; off >>= 1) {
        if (t < off) red2[t] += red2[t + off];
        __syncthreads();
    }
    float s = red2[0];
    out[(size_t)g * 256 + t] = v - m - logf(s);
}

extern "C" void kernel_launch(void* const* d_in, const int* in_sizes, int n_in,
                              void* d_out, int out_size, void* d_ws, size_t ws_size,
                              hipStream_t stream) {
    const float* x  = (const float*)d_in[0];
    const float* W1 = (const float*)d_in[1];
    const float* b1 = (const float*)d_in[2];
    const float* W2 = (const float*)d_in[3];
    const float* b2 = (const float*)d_in[4];
    const int* edge_index = (const int*)d_in[5];
    const int* batch = (const int*)d_in[6];
    float* out = (float*)d_out;

    const int N = in_sizes[6];
    const int E = in_sizes[5] / 2;
    const int H = in_sizes[2];        // 256
    const int G = out_size / H;       // 512
    const int K1 = in_sizes[1] / H;   // 128
    const int* src = edge_index;
    const int* dst = edge_index + E;

    // workspace layout (indeg and fill adjacent -> one memset covers both)
    char* p = (char*)d_ws;
    auto alloc = [&](size_t bytes) {
        char* r = p;
        p += (bytes + 255) & ~(size_t)255;
        return r;
    };
    int*   indeg    = (int*)alloc((size_t)N * 4);
    int*   fill     = (int*)alloc((size_t)N * 4);
    int*   rowstart = (int*)alloc((size_t)(N + 1) * 4);
    int*   bsum     = (int*)alloc(256 * 4);
    float* dinv     = (float*)alloc((size_t)N * 4);
    int*   gstart   = (int*)alloc((size_t)(G + 1) * 4);
    int*   csr_src  = (int*)alloc((size_t)E * 4);
    unsigned short* xb    = (unsigned short*)alloc((size_t)N * K1 * 2);  // bf16(x*dinv)
    unsigned short* yb    = (unsigned short*)alloc((size_t)N * K1 * 2);  // agg1 out
    unsigned short* h1    = (unsigned short*)alloc((size_t)N * H * 2);   // layer1 out
    unsigned short* hsbuf = (unsigned short*)alloc((size_t)N * H * 2);   // gemm2 out
    unsigned short* h2    = (unsigned short*)alloc((size_t)N * H * 2);   // layer2 out
    unsigned short* w1h = (unsigned short*)alloc((size_t)K1 * H * 2);
    unsigned short* w1l = (unsigned short*)alloc((size_t)K1 * H * 2);
    unsigned short* w2h = (unsigned short*)alloc((size_t)H * H * 2);
    unsigned short* w2l = (unsigned short*)alloc((size_t)H * H * 2);

    size_t zspan = (size_t)((char*)(fill + N) - (char*)indeg);
    hipMemsetAsync(indeg, 0, zspan, stream);

    const int eb = (E + 255) / 256;
    const int nb = (N + 255) / 256;

    count_kernel<<<eb, 256, 0, stream>>>(dst, indeg, E);
    scanA<<<nb, 256, 0, stream>>>(indeg, rowstart, bsum, N);
    scanB<<<1, 256, 0, stream>>>(bsum, nb);
    scanC<<<nb, 256, 0, stream>>>(rowstart, bsum, indeg, dinv, N, E);
    fill_csr<<<eb, 256, 0, stream>>>(src, dst, rowstart, fill, csr_src, E);
    gstart_kernel<<<(G + 1 + 255) / 256, 256, 0, stream>>>(batch, gstart, N, G);
    conv_w2<<<((K1 + H) * H + 255) / 256, 256, 0, stream>>>(W1, K1, w1h, w1l,
                                                            W2, H, w2h, w2l);
    cast_scale<<<(N * K1 / 4 + 255) / 256, 256, 0, stream>>>(x, dinv, xb, N * K1 / 4);

    const int gb = (N + 63) / 64;
    const int ab = (N + 3) / 4;
    // layer 1 (aggregate-first): y = bf16(dinv*gather(xb)); h1 = relu(y@W1+b1)
    agg_kernel<2><<<ab, 256, 0, stream>>>(xb, rowstart, csr_src, dinv, nullptr, yb, N);
    gemm_mfma<128, 1><<<gb, 256, 0, stream>>>(yb, w1h, w1l, nullptr, b1, h1, N);
    // layer 2: hs = bf16((h1@W2)*dinv); h2 = bf16(dinv*gather(hs) + b2)
    gemm_mfma<256, 0><<<gb, 256, 0, stream>>>(h1, w2h, w2l, dinv, nullptr, hsbuf, N);
    agg_kernel<4><<<ab, 256, 0, stream>>>(hsbuf, rowstart, csr_src, dinv, b2, h2, N);
    // fused pooling + log_softmax
    pool_lsm_kernel<<<G, 256, 0, stream>>>(h2, gstart, out);
}